// Round 5
// baseline (133.373 us; speedup 1.0000x reference)
//
#include <hip/hip_runtime.h>
#include <stdint.h>

typedef __attribute__((ext_vector_type(8))) short bf16x8;
typedef __attribute__((ext_vector_type(4))) short bf16x4;
typedef __attribute__((ext_vector_type(4))) float f32x4;

#define CHUNK_SHIFT 11            // source chunk = 2048 nodes (2 MB of bf16[512] rows)
#define NCHUNK 5                  // ceil(10000 / 2048)

static __device__ __forceinline__ unsigned short f2bf(float f) {
    unsigned int u = __float_as_uint(f);
    u = u + 0x7FFFu + ((u >> 16) & 1u);   // round-to-nearest-even
    return (unsigned short)(u >> 16);
}
static __device__ __forceinline__ float bf2f(short b) {
    return __uint_as_float(((unsigned int)(unsigned short)b) << 16);
}

#define GLD_LDS16(g, l) __builtin_amdgcn_global_load_lds( \
    (const __attribute__((address_space(1))) uint32_t*)(g), \
    (__attribute__((address_space(3))) uint32_t*)(l), 16, 0, 0)

// ---- fused setup: hist2 | conv_x | transpose W1 | transpose W2 ------------
// blocks: [0,625) hist2, [625,5625) conv_x, [5625,6649) tW1, [6649,7161) tW2

__global__ __launch_bounds__(256) void k_setup(
    const int* __restrict__ src, const int* __restrict__ tgt,
    int* __restrict__ hist2, int E,
    const float* __restrict__ x, unsigned short* __restrict__ xb, int total4,
    const float* __restrict__ W1, unsigned short* __restrict__ w1t,
    const float* __restrict__ W2, unsigned short* __restrict__ w2t)
{
    const int bid = blockIdx.x;
    const int tid = threadIdx.x;
    if (bid < 625) {                                   // chunked histogram
        int e = bid * 256 + tid;
        if (e < E) {
            int key = tgt[e] * NCHUNK + (src[e] >> CHUNK_SHIFT);
            atomicAdd(&hist2[key], 1);
        }
    } else if (bid < 5625) {                           // conv x -> bf16
        int i = (bid - 625) * 256 + tid;
        if (i < total4) {
            float4 v = ((const float4*)x)[i];
            ushort4 o;
            o.x = f2bf(v.x); o.y = f2bf(v.y); o.z = f2bf(v.z); o.w = f2bf(v.w);
            ((ushort4*)xb)[i] = o;
        }
    } else if (bid < 6649) {                           // W1[512][512] -> w1t[n][k]
        int idx = (bid - 5625) * 256 + tid;            // read-coalesced
        int k = idx >> 9, n = idx & 511;
        w1t[(size_t)n * 512 + k] = f2bf(W1[idx]);
    } else {                                           // W2[512][256] -> w2t[n][k]
        int idx = (bid - 6649) * 256 + tid;
        int k = idx >> 8, n = idx & 255;
        w2t[(size_t)n * 512 + k] = f2bf(W2[idx]);
    }
}

// ---- scan over node degrees; emit per-(node,chunk) segment starts ---------
// row_ptr2[t*NCHUNK+c] = start of (t,c) segment; row_ptr2[N*NCHUNK] = E.
// row_fill2 = copy for the atomic fill. dinv[t] = rsqrt(deg+1).

__global__ __launch_bounds__(1024) void k_scan(
    const int* __restrict__ hist2, int* __restrict__ row_ptr2,
    int* __restrict__ row_fill2, float* __restrict__ dinv, int N)
{
    __shared__ int wsum[16];
    const int tid = threadIdx.x;
    const int lane = tid & 63, wid = tid >> 6;
    const int CH = 10;
    const int base = tid * CH;
    int local[CH];
    int sum = 0;
#pragma unroll
    for (int j = 0; j < CH; ++j) {
        int idx = base + j;
        int deg = 0;
        if (idx < N) {
#pragma unroll
            for (int c = 0; c < NCHUNK; ++c) deg += hist2[idx * NCHUNK + c];
            dinv[idx] = rsqrtf((float)(deg + 1));
        }
        local[j] = sum;
        sum += deg;
    }
    int inc = sum;
    for (int off = 1; off < 64; off <<= 1) {
        int v = __shfl_up(inc, off, 64);
        if (lane >= off) inc += v;
    }
    if (lane == 63) wsum[wid] = inc;
    __syncthreads();
    if (wid == 0) {
        int w = (lane < 16) ? wsum[lane] : 0;
        for (int off = 1; off < 16; off <<= 1) {
            int v = __shfl_up(w, off, 64);
            if (lane >= off) w += v;
        }
        if (lane < 16) wsum[lane] = w;   // inclusive wave prefix
    }
    __syncthreads();
    const int wpre = (wid == 0) ? 0 : wsum[wid - 1];
    const int texcl = wpre + inc - sum;
#pragma unroll
    for (int j = 0; j < CH; ++j) {
        int idx = base + j;
        if (idx < N) {
            int p = texcl + local[j];
#pragma unroll
            for (int c = 0; c < NCHUNK; ++c) {
                row_ptr2[idx * NCHUNK + c] = p;
                row_fill2[idx * NCHUNK + c] = p;
                p += hist2[idx * NCHUNK + c];
            }
        }
    }
    if (tid == 1023) row_ptr2[N * NCHUNK] = wsum[15];
}

__global__ void k_fill(const int* __restrict__ src, const int* __restrict__ tgt,
                       int* __restrict__ row_fill2, int* __restrict__ esrc, int E) {
    int e = blockIdx.x * blockDim.x + threadIdx.x;
    if (e < E) {
        int s = src[e];
        int key = tgt[e] * NCHUNK + (s >> CHUNK_SHIFT);
        int pos = atomicAdd(&row_fill2[key], 1);
        esrc[pos] = s;
    }
}

// ---- bf16 MFMA GEMM: C = bf16( [dinv[m]] * A[M,K] Bt[N,K]^T ) -------------
// tile 64x128, BK=64, 4 waves (2x2) each owning 32x64; XCD-chunked swizzle.

template<bool SCALE_ROW>
__global__ __launch_bounds__(256) void k_gemm(
    const short* __restrict__ A,
    const short* __restrict__ Bt,
    const float* __restrict__ dinv,
    unsigned short* __restrict__ C,
    int M, int N, int K, int ncol, int q, int r)
{
    __shared__ char smem[24576];
    char* smA = smem;
    char* smB = smem + 8192;

    const int orig = blockIdx.x;
    const int xcd = orig & 7, loc = orig >> 3;
    const int wg = (xcd < r ? xcd * (q + 1) : r * (q + 1) + (xcd - r) * q) + loc;
    const int rowbase = (wg / ncol) * 64;
    const int colbase = (wg % ncol) * 128;

    const int tid  = threadIdx.x;
    const int lane = tid & 63;
    const int wave = tid >> 6;

    const int lrow = (lane >> 3);
    const int scol = ((lane & 7) ^ lrow) << 3;
    const int rA0 = wave * 8 + lrow;
    int gA0 = rowbase + rA0;          if (gA0 >= M) gA0 = M - 1;
    int gA1 = rowbase + rA0 + 32;     if (gA1 >= M) gA1 = M - 1;
    const size_t offA0 = (size_t)gA0 * K + scol;
    const size_t offA1 = (size_t)gA1 * K + scol;
    size_t offB[4];
#pragma unroll
    for (int c = 0; c < 4; ++c)
        offB[c] = (size_t)(colbase + c * 32 + rA0) * K + scol;

    char* const dA0 = smA + wave * 1024;
    char* const dA1 = smA + 4096 + wave * 1024;
    char* dB[4];
#pragma unroll
    for (int c = 0; c < 4; ++c) dB[c] = smB + c * 4096 + wave * 1024;

    const int wr = (wave >> 1) * 32;
    const int wc = (wave & 1) * 64;
    const int fr = lane & 15;
    const int fs = lane >> 4;

    f32x4 acc[2][4];
#pragma unroll
    for (int m = 0; m < 2; ++m)
#pragma unroll
        for (int n = 0; n < 4; ++n)
            acc[m][n] = (f32x4){0.f, 0.f, 0.f, 0.f};

    for (int k0 = 0; k0 < K; k0 += 64) {
        GLD_LDS16(A + offA0 + k0, dA0);
        GLD_LDS16(A + offA1 + k0, dA1);
#pragma unroll
        for (int c = 0; c < 4; ++c)
            GLD_LDS16(Bt + offB[c] + k0, dB[c]);
        __syncthreads();

        bf16x8 a[2][2], b[4][2];
#pragma unroll
        for (int m = 0; m < 2; ++m)
#pragma unroll
            for (int ks = 0; ks < 2; ++ks) {
                int rr = wr + m * 16 + fr;
                int s = ks * 4 + fs;
                a[m][ks] = *(const bf16x8*)(smA + rr * 128 + ((s ^ (rr & 7)) << 4));
            }
#pragma unroll
        for (int n = 0; n < 4; ++n)
#pragma unroll
            for (int ks = 0; ks < 2; ++ks) {
                int rr = wc + n * 16 + fr;
                int s = ks * 4 + fs;
                b[n][ks] = *(const bf16x8*)(smB + rr * 128 + ((s ^ (rr & 7)) << 4));
            }
#pragma unroll
        for (int m = 0; m < 2; ++m)
#pragma unroll
            for (int n = 0; n < 4; ++n)
#pragma unroll
                for (int ks = 0; ks < 2; ++ks)
                    acc[m][n] = __builtin_amdgcn_mfma_f32_16x16x32_bf16(
                        a[m][ks], b[n][ks], acc[m][n], 0, 0, 0);
        __syncthreads();
    }

    const int orow0 = rowbase + wr + fs * 4;
    const int ocol0 = colbase + wc + fr;
#pragma unroll
    for (int m = 0; m < 2; ++m)
#pragma unroll
        for (int i = 0; i < 4; ++i) {
            int row = orow0 + m * 16 + i;
            if (row < M) {
                float sc = SCALE_ROW ? dinv[row] : 1.0f;
#pragma unroll
                for (int n = 0; n < 4; ++n)
                    C[(size_t)row * N + ocol0 + n * 16] = f2bf(sc * acc[m][n][i]);
            }
        }
}

// ---- aggregation: 1 node per wave; edge list is chunk-ordered -------------
// agg1: pre = dt*(sum u[s] + u[t]); h' = dt*pre^2 -> bf16 [Nn][512]

__global__ __launch_bounds__(256) void k_agg1(
    const unsigned short* __restrict__ xwb,
    const int* __restrict__ row_ptr2, const int* __restrict__ esrc,
    const float* __restrict__ dinv,
    unsigned short* __restrict__ hb, int Nn)
{
    const int t = blockIdx.x * 4 + (threadIdx.x >> 6);
    if (t >= Nn) return;
    const int lane = threadIdx.x & 63;
    const float dt = dinv[t];

    float acc[8];
    bf16x8 v = *(const bf16x8*)(xwb + (size_t)t * 512 + lane * 8);
#pragma unroll
    for (int j = 0; j < 8; ++j) acc[j] = bf2f(v[j]);

    int e = row_ptr2[t * NCHUNK];
    const int e1 = row_ptr2[t * NCHUNK + NCHUNK];
    for (; e + 7 < e1; e += 8) {
        int s[8];
#pragma unroll
        for (int j = 0; j < 8; ++j) s[j] = esrc[e + j];
        bf16x8 u[8];
#pragma unroll
        for (int j = 0; j < 8; ++j)
            u[j] = *(const bf16x8*)(xwb + (size_t)s[j] * 512 + lane * 8);
#pragma unroll
        for (int j = 0; j < 8; ++j)
#pragma unroll
            for (int c = 0; c < 8; ++c) acc[c] += bf2f(u[j][c]);
    }
    for (; e + 3 < e1; e += 4) {
        int s[4];
#pragma unroll
        for (int j = 0; j < 4; ++j) s[j] = esrc[e + j];
        bf16x8 u[4];
#pragma unroll
        for (int j = 0; j < 4; ++j)
            u[j] = *(const bf16x8*)(xwb + (size_t)s[j] * 512 + lane * 8);
#pragma unroll
        for (int j = 0; j < 4; ++j)
#pragma unroll
            for (int c = 0; c < 8; ++c) acc[c] += bf2f(u[j][c]);
    }
    for (; e < e1; ++e) {
        int s = esrc[e];
        bf16x8 u = *(const bf16x8*)(xwb + (size_t)s * 512 + lane * 8);
#pragma unroll
        for (int c = 0; c < 8; ++c) acc[c] += bf2f(u[c]);
    }

    bf16x8 o;
#pragma unroll
    for (int c = 0; c < 8; ++c) {
        float pre = dt * acc[c];
        o[c] = (short)f2bf(dt * pre * pre);
    }
    *(bf16x8*)(hb + (size_t)t * 512 + lane * 8) = o;
}

// agg2: out[t] = dt*(sum xw2'[s] + xw2'[t]); bf16 in [Nn][256], f32 out
__global__ __launch_bounds__(256) void k_agg2(
    const unsigned short* __restrict__ xwb,
    const int* __restrict__ row_ptr2, const int* __restrict__ esrc,
    const float* __restrict__ dinv,
    float* __restrict__ out, int Nn)
{
    const int t = blockIdx.x * 4 + (threadIdx.x >> 6);
    if (t >= Nn) return;
    const int lane = threadIdx.x & 63;
    const float dt = dinv[t];

    float acc[4];
    bf16x4 v = *(const bf16x4*)(xwb + (size_t)t * 256 + lane * 4);
#pragma unroll
    for (int j = 0; j < 4; ++j) acc[j] = bf2f(v[j]);

    int e = row_ptr2[t * NCHUNK];
    const int e1 = row_ptr2[t * NCHUNK + NCHUNK];
    for (; e + 7 < e1; e += 8) {
        int s[8];
#pragma unroll
        for (int j = 0; j < 8; ++j) s[j] = esrc[e + j];
        bf16x4 u[8];
#pragma unroll
        for (int j = 0; j < 8; ++j)
            u[j] = *(const bf16x4*)(xwb + (size_t)s[j] * 256 + lane * 4);
#pragma unroll
        for (int j = 0; j < 8; ++j)
#pragma unroll
            for (int c = 0; c < 4; ++c) acc[c] += bf2f(u[j][c]);
    }
    for (; e + 3 < e1; e += 4) {
        int s[4];
#pragma unroll
        for (int j = 0; j < 4; ++j) s[j] = esrc[e + j];
        bf16x4 u[4];
#pragma unroll
        for (int j = 0; j < 4; ++j)
            u[j] = *(const bf16x4*)(xwb + (size_t)s[j] * 256 + lane * 4);
#pragma unroll
        for (int j = 0; j < 4; ++j)
#pragma unroll
            for (int c = 0; c < 4; ++c) acc[c] += bf2f(u[j][c]);
    }
    for (; e < e1; ++e) {
        int s = esrc[e];
        bf16x4 u = *(const bf16x4*)(xwb + (size_t)s * 256 + lane * 4);
#pragma unroll
        for (int c = 0; c < 4; ++c) acc[c] += bf2f(u[c]);
    }

    float4 rout;
    rout.x = dt * acc[0]; rout.y = dt * acc[1];
    rout.z = dt * acc[2]; rout.w = dt * acc[3];
    ((float4*)(out + (size_t)t * 256))[lane] = rout;
}

// ---- launch ---------------------------------------------------------------

extern "C" void kernel_launch(void* const* d_in, const int* in_sizes, int n_in,
                              void* d_out, int out_size, void* d_ws, size_t ws_size,
                              hipStream_t stream) {
    const float* x   = (const float*)d_in[0];
    const int*  eidx = (const int*)d_in[1];
    const float* W1  = (const float*)d_in[2];
    const float* W2  = (const float*)d_in[3];
    float* out = (float*)d_out;

    const int DIN = 512, DHID = 512, DOUT = 256;
    const int Nn = in_sizes[0] / DIN;   // 10000
    const int E  = in_sizes[1] / 2;     // 160000
    const int* src = eidx;
    const int* tgt = eidx + E;

    char* ws = (char*)d_ws;
    size_t off = 0;
    auto alloc = [&](size_t bytes) -> char* {
        off = (off + 255) & ~(size_t)255;
        char* p = ws + off;
        off += bytes;
        return p;
    };

    int*   hist2     = (int*)  alloc((size_t)Nn * NCHUNK * 4);
    int*   row_ptr2  = (int*)  alloc(((size_t)Nn * NCHUNK + 1) * 4);
    int*   row_fill2 = (int*)  alloc((size_t)Nn * NCHUNK * 4);
    float* dinv      = (float*)alloc((size_t)Nn * 4);
    int*   esrc      = (int*)  alloc((size_t)E * 4);
    unsigned short* xb   = (unsigned short*)alloc((size_t)Nn * DIN * 2);
    unsigned short* w1t  = (unsigned short*)alloc((size_t)DIN * DHID * 2);
    unsigned short* w2t  = (unsigned short*)alloc((size_t)DHID * DOUT * 2);
    unsigned short* xwb  = (unsigned short*)alloc((size_t)Nn * DHID * 2);
    unsigned short* hb   = (unsigned short*)alloc((size_t)Nn * DHID * 2);
    unsigned short* xw2b = (unsigned short*)alloc((size_t)Nn * DOUT * 2);

    hipMemsetAsync(hist2, 0, (size_t)Nn * NCHUNK * 4, stream);

    const int total4 = Nn * DIN / 4;
    k_setup<<<7161, 256, 0, stream>>>(src, tgt, hist2, E, x, xb, total4, W1, w1t, W2, w2t);
    k_scan<<<1, 1024, 0, stream>>>(hist2, row_ptr2, row_fill2, dinv, Nn);
    k_fill<<<(E + 255) / 256, 256, 0, stream>>>(src, tgt, row_fill2, esrc, E);

    // layer 1
    {
        const int nrow = (Nn + 63) / 64, ncol = DHID / 128;
        const int nwg = nrow * ncol;
        k_gemm<true><<<nwg, 256, 0, stream>>>(
            (const short*)xb, (const short*)w1t, dinv, xwb,
            Nn, DHID, DIN, ncol, nwg >> 3, nwg & 7);
    }
    k_agg1<<<(Nn + 3) / 4, 256, 0, stream>>>(xwb, row_ptr2, esrc, dinv, hb, Nn);

    // layer 2
    {
        const int nrow = (Nn + 63) / 64, ncol = DOUT / 128;
        const int nwg = nrow * ncol;
        k_gemm<false><<<nwg, 256, 0, stream>>>(
            (const short*)hb, (const short*)w2t, dinv, xw2b,
            Nn, DOUT, DHID, ncol, nwg >> 3, nwg & 7);
    }
    k_agg2<<<(Nn + 3) / 4, 256, 0, stream>>>(xw2b, row_ptr2, esrc, dinv, out, Nn);
}

// Round 6
// 99.449 us; speedup vs baseline: 1.3411x; 1.3411x over previous
//
#include <hip/hip_runtime.h>
#include <stdint.h>

typedef __attribute__((ext_vector_type(8))) short bf16x8;
typedef __attribute__((ext_vector_type(4))) short bf16x4;
typedef __attribute__((ext_vector_type(4))) float f32x4;

static __device__ __forceinline__ unsigned short f2bf(float f) {
    unsigned int u = __float_as_uint(f);
    u = u + 0x7FFFu + ((u >> 16) & 1u);   // round-to-nearest-even
    return (unsigned short)(u >> 16);
}
static __device__ __forceinline__ float bf2f(short b) {
    return __uint_as_float(((unsigned int)(unsigned short)b) << 16);
}

#define GLD_LDS16(g, l) __builtin_amdgcn_global_load_lds( \
    (const __attribute__((address_space(1))) uint32_t*)(g), \
    (__attribute__((address_space(3))) uint32_t*)(l), 16, 0, 0)

// ---- fused setup: hist | conv_x | transpose W1 | transpose W2 -------------
// blocks: [0,625) hist, [625,5625) conv_x, [5625,6649) tW1, [6649,7161) tW2

__global__ __launch_bounds__(256) void k_setup(
    const int* __restrict__ tgt, int* __restrict__ cnt, int E,
    const float* __restrict__ x, unsigned short* __restrict__ xb, int total4,
    const float* __restrict__ W1, unsigned short* __restrict__ w1t,
    const float* __restrict__ W2, unsigned short* __restrict__ w2t)
{
    const int bid = blockIdx.x;
    const int tid = threadIdx.x;
    if (bid < 625) {                                   // hist
        int e = bid * 256 + tid;
        if (e < E) atomicAdd(&cnt[tgt[e]], 1);
    } else if (bid < 5625) {                           // conv x -> bf16
        int i = (bid - 625) * 256 + tid;
        if (i < total4) {
            float4 v = ((const float4*)x)[i];
            ushort4 o;
            o.x = f2bf(v.x); o.y = f2bf(v.y); o.z = f2bf(v.z); o.w = f2bf(v.w);
            ((ushort4*)xb)[i] = o;
        }
    } else if (bid < 6649) {                           // W1[512][512] -> w1t[n][k]
        int idx = (bid - 5625) * 256 + tid;            // read-coalesced
        int k = idx >> 9, n = idx & 511;
        w1t[(size_t)n * 512 + k] = f2bf(W1[idx]);
    } else {                                           // W2[512][256] -> w2t[n][k]
        int idx = (bid - 6649) * 256 + tid;
        int k = idx >> 8, n = idx & 255;
        w2t[(size_t)n * 512 + k] = f2bf(W2[idx]);
    }
}

// ---- parallel scan: A (block-local prefix) -> B (block sums) -> C (add) ---

__global__ __launch_bounds__(256) void k_scanA(
    const int* __restrict__ cnt, int* __restrict__ row_ptr,
    float* __restrict__ dinv, int* __restrict__ blocksum, int N)
{
    __shared__ int ws[4];
    const int i = blockIdx.x * 256 + threadIdx.x;
    const int lane = threadIdx.x & 63, wid = threadIdx.x >> 6;
    int v = 0;
    if (i < N) { v = cnt[i]; dinv[i] = rsqrtf((float)(v + 1)); }
    int inc = v;
    for (int off = 1; off < 64; off <<= 1) {
        int u = __shfl_up(inc, off, 64);
        if (lane >= off) inc += u;
    }
    if (lane == 63) ws[wid] = inc;
    __syncthreads();
    int wpre = 0;
#pragma unroll
    for (int w = 0; w < 4; ++w) wpre += (w < wid) ? ws[w] : 0;
    if (i < N) row_ptr[i] = wpre + inc - v;     // block-local exclusive
    if (threadIdx.x == 255) blocksum[blockIdx.x] = wpre + inc;
}

__global__ void k_scanB(const int* __restrict__ blocksum, int* __restrict__ blockoff,
                        int* __restrict__ row_ptr, int N, int NB)
{
    const int lane = threadIdx.x;   // 64 threads, NB <= 64
    int v = (lane < NB) ? blocksum[lane] : 0;
    int inc = v;
    for (int off = 1; off < 64; off <<= 1) {
        int u = __shfl_up(inc, off, 64);
        if (lane >= off) inc += u;
    }
    if (lane < NB) blockoff[lane] = inc - v;    // exclusive block offset
    if (lane == 63) row_ptr[N] = inc;           // total = E
}

__global__ __launch_bounds__(256) void k_scanC(
    int* __restrict__ row_ptr, int* __restrict__ row_fill,
    const int* __restrict__ blockoff, int N)
{
    const int i = blockIdx.x * 256 + threadIdx.x;
    if (i < N) {
        int rp = row_ptr[i] + blockoff[blockIdx.x];
        row_ptr[i] = rp;
        row_fill[i] = rp;
    }
}

__global__ void k_fill(const int* __restrict__ src, const int* __restrict__ tgt,
                       int* __restrict__ row_fill, int* __restrict__ esrc, int E) {
    int e = blockIdx.x * blockDim.x + threadIdx.x;
    if (e < E) {
        int pos = atomicAdd(&row_fill[tgt[e]], 1);
        esrc[pos] = src[e];
    }
}

// ---- bf16 MFMA GEMM: C = bf16( [dinv[m]] * A[M,K] Bt[N,K]^T ) -------------
// tile 64x128, BK=64, 4 waves (2x2) each owning 32x64; XCD-chunked swizzle.

template<bool SCALE_ROW>
__global__ __launch_bounds__(256) void k_gemm(
    const short* __restrict__ A,
    const short* __restrict__ Bt,
    const float* __restrict__ dinv,
    unsigned short* __restrict__ C,
    int M, int N, int K, int ncol, int q, int r)
{
    __shared__ char smem[24576];
    char* smA = smem;
    char* smB = smem + 8192;

    const int orig = blockIdx.x;
    const int xcd = orig & 7, loc = orig >> 3;
    const int wg = (xcd < r ? xcd * (q + 1) : r * (q + 1) + (xcd - r) * q) + loc;
    const int rowbase = (wg / ncol) * 64;
    const int colbase = (wg % ncol) * 128;

    const int tid  = threadIdx.x;
    const int lane = tid & 63;
    const int wave = tid >> 6;

    const int lrow = (lane >> 3);
    const int scol = ((lane & 7) ^ lrow) << 3;
    const int rA0 = wave * 8 + lrow;
    int gA0 = rowbase + rA0;          if (gA0 >= M) gA0 = M - 1;
    int gA1 = rowbase + rA0 + 32;     if (gA1 >= M) gA1 = M - 1;
    const size_t offA0 = (size_t)gA0 * K + scol;
    const size_t offA1 = (size_t)gA1 * K + scol;
    size_t offB[4];
#pragma unroll
    for (int c = 0; c < 4; ++c)
        offB[c] = (size_t)(colbase + c * 32 + rA0) * K + scol;

    char* const dA0 = smA + wave * 1024;
    char* const dA1 = smA + 4096 + wave * 1024;
    char* dB[4];
#pragma unroll
    for (int c = 0; c < 4; ++c) dB[c] = smB + c * 4096 + wave * 1024;

    const int wr = (wave >> 1) * 32;
    const int wc = (wave & 1) * 64;
    const int fr = lane & 15;
    const int fs = lane >> 4;

    f32x4 acc[2][4];
#pragma unroll
    for (int m = 0; m < 2; ++m)
#pragma unroll
        for (int n = 0; n < 4; ++n)
            acc[m][n] = (f32x4){0.f, 0.f, 0.f, 0.f};

    for (int k0 = 0; k0 < K; k0 += 64) {
        GLD_LDS16(A + offA0 + k0, dA0);
        GLD_LDS16(A + offA1 + k0, dA1);
#pragma unroll
        for (int c = 0; c < 4; ++c)
            GLD_LDS16(Bt + offB[c] + k0, dB[c]);
        __syncthreads();

        bf16x8 a[2][2], b[4][2];
#pragma unroll
        for (int m = 0; m < 2; ++m)
#pragma unroll
            for (int ks = 0; ks < 2; ++ks) {
                int rr = wr + m * 16 + fr;
                int s = ks * 4 + fs;
                a[m][ks] = *(const bf16x8*)(smA + rr * 128 + ((s ^ (rr & 7)) << 4));
            }
#pragma unroll
        for (int n = 0; n < 4; ++n)
#pragma unroll
            for (int ks = 0; ks < 2; ++ks) {
                int rr = wc + n * 16 + fr;
                int s = ks * 4 + fs;
                b[n][ks] = *(const bf16x8*)(smB + rr * 128 + ((s ^ (rr & 7)) << 4));
            }
#pragma unroll
        for (int m = 0; m < 2; ++m)
#pragma unroll
            for (int n = 0; n < 4; ++n)
#pragma unroll
                for (int ks = 0; ks < 2; ++ks)
                    acc[m][n] = __builtin_amdgcn_mfma_f32_16x16x32_bf16(
                        a[m][ks], b[n][ks], acc[m][n], 0, 0, 0);
        __syncthreads();
    }

    const int orow0 = rowbase + wr + fs * 4;
    const int ocol0 = colbase + wc + fr;
#pragma unroll
    for (int m = 0; m < 2; ++m)
#pragma unroll
        for (int i = 0; i < 4; ++i) {
            int row = orow0 + m * 16 + i;
            if (row < M) {
                float sc = SCALE_ROW ? dinv[row] : 1.0f;
#pragma unroll
                for (int n = 0; n < 4; ++n)
                    C[(size_t)row * N + ocol0 + n * 16] = f2bf(sc * acc[m][n][i]);
            }
        }
}

// ---- aggregation: 256-thread blocks, 1 node per wave, unroll 8 ------------
// agg1: pre = dt*(sum u[s] + u[t]); h' = dt*pre^2 -> bf16 [Nn][512]

__global__ __launch_bounds__(256) void k_agg1(
    const unsigned short* __restrict__ xwb,
    const int* __restrict__ row_ptr, const int* __restrict__ esrc,
    const float* __restrict__ dinv,
    unsigned short* __restrict__ hb, int Nn)
{
    const int t = blockIdx.x * 4 + (threadIdx.x >> 6);
    if (t >= Nn) return;
    const int lane = threadIdx.x & 63;
    const float dt = dinv[t];

    float acc[8];
    bf16x8 v = *(const bf16x8*)(xwb + (size_t)t * 512 + lane * 8);
#pragma unroll
    for (int j = 0; j < 8; ++j) acc[j] = bf2f(v[j]);

    int e = row_ptr[t];
    const int e1 = row_ptr[t + 1];
    for (; e + 7 < e1; e += 8) {
        int s[8];
#pragma unroll
        for (int j = 0; j < 8; ++j) s[j] = esrc[e + j];
        bf16x8 u[8];
#pragma unroll
        for (int j = 0; j < 8; ++j)
            u[j] = *(const bf16x8*)(xwb + (size_t)s[j] * 512 + lane * 8);
#pragma unroll
        for (int j = 0; j < 8; ++j)
#pragma unroll
            for (int c = 0; c < 8; ++c) acc[c] += bf2f(u[j][c]);
    }
    for (; e + 3 < e1; e += 4) {
        int s[4];
#pragma unroll
        for (int j = 0; j < 4; ++j) s[j] = esrc[e + j];
        bf16x8 u[4];
#pragma unroll
        for (int j = 0; j < 4; ++j)
            u[j] = *(const bf16x8*)(xwb + (size_t)s[j] * 512 + lane * 8);
#pragma unroll
        for (int j = 0; j < 4; ++j)
#pragma unroll
            for (int c = 0; c < 8; ++c) acc[c] += bf2f(u[j][c]);
    }
    for (; e < e1; ++e) {
        int s = esrc[e];
        bf16x8 u = *(const bf16x8*)(xwb + (size_t)s * 512 + lane * 8);
#pragma unroll
        for (int c = 0; c < 8; ++c) acc[c] += bf2f(u[c]);
    }

    bf16x8 o;
#pragma unroll
    for (int c = 0; c < 8; ++c) {
        float pre = dt * acc[c];
        o[c] = (short)f2bf(dt * pre * pre);
    }
    *(bf16x8*)(hb + (size_t)t * 512 + lane * 8) = o;
}

// agg2: out[t] = dt*(sum xw2'[s] + xw2'[t]); bf16 in [Nn][256], f32 out
__global__ __launch_bounds__(256) void k_agg2(
    const unsigned short* __restrict__ xwb,
    const int* __restrict__ row_ptr, const int* __restrict__ esrc,
    const float* __restrict__ dinv,
    float* __restrict__ out, int Nn)
{
    const int t = blockIdx.x * 4 + (threadIdx.x >> 6);
    if (t >= Nn) return;
    const int lane = threadIdx.x & 63;
    const float dt = dinv[t];

    float acc[4];
    bf16x4 v = *(const bf16x4*)(xwb + (size_t)t * 256 + lane * 4);
#pragma unroll
    for (int j = 0; j < 4; ++j) acc[j] = bf2f(v[j]);

    int e = row_ptr[t];
    const int e1 = row_ptr[t + 1];
    for (; e + 7 < e1; e += 8) {
        int s[8];
#pragma unroll
        for (int j = 0; j < 8; ++j) s[j] = esrc[e + j];
        bf16x4 u[8];
#pragma unroll
        for (int j = 0; j < 8; ++j)
            u[j] = *(const bf16x4*)(xwb + (size_t)s[j] * 256 + lane * 4);
#pragma unroll
        for (int j = 0; j < 8; ++j)
#pragma unroll
            for (int c = 0; c < 4; ++c) acc[c] += bf2f(u[j][c]);
    }
    for (; e + 3 < e1; e += 4) {
        int s[4];
#pragma unroll
        for (int j = 0; j < 4; ++j) s[j] = esrc[e + j];
        bf16x4 u[4];
#pragma unroll
        for (int j = 0; j < 4; ++j)
            u[j] = *(const bf16x4*)(xwb + (size_t)s[j] * 256 + lane * 4);
#pragma unroll
        for (int j = 0; j < 4; ++j)
#pragma unroll
            for (int c = 0; c < 4; ++c) acc[c] += bf2f(u[j][c]);
    }
    for (; e < e1; ++e) {
        int s = esrc[e];
        bf16x4 u = *(const bf16x4*)(xwb + (size_t)s * 256 + lane * 4);
#pragma unroll
        for (int c = 0; c < 4; ++c) acc[c] += bf2f(u[c]);
    }

    float4 rout;
    rout.x = dt * acc[0]; rout.y = dt * acc[1];
    rout.z = dt * acc[2]; rout.w = dt * acc[3];
    ((float4*)(out + (size_t)t * 256))[lane] = rout;
}

// ---- launch ---------------------------------------------------------------

extern "C" void kernel_launch(void* const* d_in, const int* in_sizes, int n_in,
                              void* d_out, int out_size, void* d_ws, size_t ws_size,
                              hipStream_t stream) {
    const float* x   = (const float*)d_in[0];
    const int*  eidx = (const int*)d_in[1];
    const float* W1  = (const float*)d_in[2];
    const float* W2  = (const float*)d_in[3];
    float* out = (float*)d_out;

    const int DIN = 512, DHID = 512, DOUT = 256;
    const int Nn = in_sizes[0] / DIN;   // 10000
    const int E  = in_sizes[1] / 2;     // 160000
    const int* src = eidx;
    const int* tgt = eidx + E;

    char* ws = (char*)d_ws;
    size_t off = 0;
    auto alloc = [&](size_t bytes) -> char* {
        off = (off + 255) & ~(size_t)255;
        char* p = ws + off;
        off += bytes;
        return p;
    };

    int*   cnt      = (int*)  alloc((size_t)Nn * 4);
    int*   row_ptr  = (int*)  alloc((size_t)(Nn + 1) * 4);
    int*   row_fill = (int*)  alloc((size_t)Nn * 4);
    float* dinv     = (float*)alloc((size_t)Nn * 4);
    int*   esrc     = (int*)  alloc((size_t)E * 4);
    int*   blocksum = (int*)  alloc(64 * 4);
    int*   blockoff = (int*)  alloc(64 * 4);
    unsigned short* xb   = (unsigned short*)alloc((size_t)Nn * DIN * 2);
    unsigned short* w1t  = (unsigned short*)alloc((size_t)DIN * DHID * 2);
    unsigned short* w2t  = (unsigned short*)alloc((size_t)DHID * DOUT * 2);
    unsigned short* xwb  = (unsigned short*)alloc((size_t)Nn * DHID * 2);
    unsigned short* hb   = (unsigned short*)alloc((size_t)Nn * DHID * 2);
    unsigned short* xw2b = (unsigned short*)alloc((size_t)Nn * DOUT * 2);

    hipMemsetAsync(cnt, 0, (size_t)Nn * 4, stream);

    const int total4 = Nn * DIN / 4;
    const int NB = (Nn + 255) / 256;    // 40
    k_setup<<<7161, 256, 0, stream>>>(tgt, cnt, E, x, xb, total4, W1, w1t, W2, w2t);
    k_scanA<<<NB, 256, 0, stream>>>(cnt, row_ptr, dinv, blocksum, Nn);
    k_scanB<<<1, 64, 0, stream>>>(blocksum, blockoff, row_ptr, Nn, NB);
    k_scanC<<<NB, 256, 0, stream>>>(row_ptr, row_fill, blockoff, Nn);
    k_fill<<<(E + 255) / 256, 256, 0, stream>>>(src, tgt, row_fill, esrc, E);

    // layer 1
    {
        const int nrow = (Nn + 63) / 64, ncol = DHID / 128;
        const int nwg = nrow * ncol;
        k_gemm<true><<<nwg, 256, 0, stream>>>(
            (const short*)xb, (const short*)w1t, dinv, xwb,
            Nn, DHID, DIN, ncol, nwg >> 3, nwg & 7);
    }
    k_agg1<<<(Nn + 3) / 4, 256, 0, stream>>>(xwb, row_ptr, esrc, dinv, hb, Nn);

    // layer 2
    {
        const int nrow = (Nn + 63) / 64, ncol = DOUT / 128;
        const int nwg = nrow * ncol;
        k_gemm<false><<<nwg, 256, 0, stream>>>(
            (const short*)hb, (const short*)w2t, dinv, xw2b,
            Nn, DOUT, DHID, ncol, nwg >> 3, nwg & 7);
    }
    k_agg2<<<(Nn + 3) / 4, 256, 0, stream>>>(xw2b, row_ptr, esrc, dinv, out, Nn);
}